// Round 13
// baseline (148.109 us; speedup 1.0000x reference)
//
#include <hip/hip_runtime.h>
#include <math.h>

// (N,C,D,H,W)=(2,32,48,48,48), K=3, T=8. All fp32 in/out (verified R5).
// R23 = R22 (best 147.0, geo 75us) + compile-time buffer selection.
// Theory: VALUBusy 32% includes per-group LDS address arithmetic that the
// runtime rb=g&1 forces: 49 gather v_adds + stage swze recompute + base
// selects per group (~600-800 instr/thread, ~20% of VALU). With rb
// compile-time, ds_read/ds_write addressing folds into the 16-bit offset
// immediate (TILE_OFF + rb*12288 + const < 65536) over the precomputed slot
// VGPR -- zero per-group address VALU. Changes: (1) #pragma unroll 2 on the
// group loop (g=2j/2j+1 makes rb/wb literals in each body); (2) stage-write
// swizzled offsets hoisted to setup (soff[6], loop-invariant). No numerics,
// layout, or schedule changes.
#define NB   2
#define CH   32
#define DHW  (48*48*48)
#define TT   8
#define EPSF 1e-6f

#define TILE_N     1521          // real halo entries 13*13*9 (1 entry = 4 ch fp16, 8B)
#define TILE_SLOTS 1536          // rounded to 16-entry blocks for the swizzle
#define TILE_BYTES (TILE_SLOTS*8) // 12288 per buffer
#define GROUPS   8               // 32 ch / 4 per group

// LDS layout (bytes): tokens [0,16384) = 256*64 ; tile 2 bufs [16384,40960)
// cbuf aliases [0,36864) = 256 rows * 36 floats (post-loop only)
#define TOK_OFF  0
#define TOK_STR  64              // 64B tokens, quadrant-XOR swizzled
#define TILE_OFF 16384
#define SMEM_SZ  (16384 + 2*TILE_BYTES)   // 40960 -> 4 blocks/CU exactly

// ws layout (float idx): Bt f16 [0,4096) floats (=8192 ushort), wf 4096, bf 4480, bm 4492
#define WS_BT_F 0
#define WS_WF   4096
#define WS_BF   4480
#define WS_BM   4492

typedef __attribute__((ext_vector_type(8))) short short8;
typedef __attribute__((ext_vector_type(8))) _Float16 half8;
typedef __attribute__((ext_vector_type(4))) float floatx4;
typedef __attribute__((ext_vector_type(2))) _Float16 h2;

struct __align__(8) q4 { h2 lo, hi; };   // 4 packed channels (8B, b64-aligned)

__device__ __forceinline__ h2 pkrtz(float a, float b) {
    return __builtin_bit_cast(h2, __builtin_amdgcn_cvt_pkrtz(a, b));
}
__device__ __forceinline__ h2 dup2(float v) {
    _Float16 h = (_Float16)v; return (h2){h, h};
}
__device__ __forceinline__ unsigned h2u(h2 v) {
    return __builtin_bit_cast(unsigned, v);
}
// bank-conflict swizzle: permute entry within its aligned 16-entry block
__device__ __forceinline__ int swze(int e) {
    return (e & ~15) | ((e ^ (e >> 4)) & 15);
}

__global__ __launch_bounds__(256) void prep_kernel(
        const float* __restrict__ w_field,
        const float* __restrict__ b_field,
        const float* __restrict__ gates,
        const float* __restrict__ w_mix,
        const float* __restrict__ b_mix,
        float* __restrict__ ws) {
    int i = blockIdx.x * 256 + threadIdx.x;    // grid 32*256 = 8192
    // Bt[o][k] f16 (RNE), k = c*8 + t, value = sigmoid(gates[t]) * w_mix[o, t*32+c]
    {
        int o = i >> 8, k = i & 255, c = k >> 3, t = k & 7;
        float sg = 1.0f / (1.0f + expf(-gates[t]));
        _Float16 hv = (_Float16)(sg * w_mix[o * 256 + t * 32 + c]);
        ((unsigned short*)(ws + WS_BT_F))[o * 256 + k] = __builtin_bit_cast(unsigned short, hv);
    }
    if (i < 384) { int c = i / 12, o = i - c * 12; ws[WS_WF + i] = w_field[o * 32 + c]; }
    if (i < 12)  ws[WS_BF + i] = b_field[i];
    if (i < 32)  ws[WS_BM + i] = b_mix[i];
}

__global__ __launch_bounds__(256) void geo_main(
        const float* __restrict__ x,
        const float* __restrict__ ws,
        float* __restrict__ out) {
    __shared__ __align__(16) char smem[SMEM_SZ];
    char* tokb  = smem + TOK_OFF;
    char* tbuf  = smem + TILE_OFF;             // 2 buffers of TILE_BYTES
    float* cbuf = (float*)smem;                // alias, post-loop only

    const int tid = threadIdx.x;
    // XCD-locality swizzle: chunk c = blockIdx&7 gets lin in [108c,108(c+1)).
    const int lin = (blockIdx.x & 7) * 108 + (blockIdx.x >> 3);
    const int bx = lin % 6, by = (lin / 6) % 6, bz = (lin / 36) % 12, n = lin / 432;
    const int lx = tid & 7, ly = (tid >> 3) & 7, lz = tid >> 6;
    const int w = bx * 8 + lx, h = by * 8 + ly, d = bz * 4 + lz;
    const int xlo = bx * 8 - 2, ylo = by * 8 - 2, zlo = bz * 4 - 2;
    const int lane = tid & 63, w64 = tid & 192;

    const float* xn = x + (size_t)n * CH * DHW;

    // ---- channel-invariant halo-load offsets + hoisted stage slots ----
    int goff[6], soff[6];
#pragma unroll
    for (int i = 0; i < 6; ++i) {
        int e  = tid + i * 256;
        soff[i] = swze(e) * 8;                 // loop-invariant swizzled stage offset
        int ee = (e < TILE_N) ? e : 0;
        int tz = ee / 169; int r0 = ee - tz * 169;
        int ty = r0 / 13;  int tx = r0 - ty * 13;
        int zg = min(max(zlo + tz, 0), 47);
        int yg = min(max(ylo + ty, 0), 47);
        int xg = min(max(xlo + tx, 0), 47);
        goff[i] = (zg * 48 + yg) * 48 + xg;
    }

    // ---- phase A: f[12] = w_field @ x(:,pos) + b_field ----
    const int pos = (d * 48 + h) * 48 + w;
    float f[12];
#pragma unroll
    for (int o = 0; o < 12; ++o) f[o] = ws[WS_BF + o];
    for (int c = 0; c < CH; ++c) {
        float xv = xn[c * DHW + pos];
        const float* wf = ws + WS_WF + c * 12;
#pragma unroll
        for (int o = 0; o < 12; ++o) f[o] = fmaf(wf[o], xv, f[o]);
    }

    // ---- per-voxel sample parameters (swizzled byte offsets) ----
    h2 fx2[6], fy2[6], fz2[6];
    int a00s[6], a00p[6], a01s[6], a01p[6];
    int a10s[6], a10p[6], a11s[6], a11p[6];
    h2 hux[3], huy[3], huz[3], hir[3], hq[3];  // packed token constants
    const float cscale = 48.0f / (48.0f + EPSF);
#pragma unroll
    for (int k = 0; k < 3; ++k) {
        float vx = f[4*k], vy = f[4*k+1], vz = f[4*k+2], s = f[4*k+3];
        float inv = 1.0f / sqrtf(vx*vx + vy*vy + vz*vz + EPSF);
        float ux = vx * inv, uy = vy * inv, uz = vz * inv;
        float r  = 0.5f + 1.5f / (1.0f + expf(-s));
        float ir = 1.0f / (r + EPSF);
        hux[k] = dup2(ux); huy[k] = dup2(uy); huz[k] = dup2(uz);
        hir[k] = dup2(0.5f * ir);
        hq[k]  = dup2(ir * ir * (1.0f / 3.0f));
#pragma unroll
        for (int sgn = 0; sgn < 2; ++sgn) {
            int   si = 2 * k + sgn;
            float sf = sgn ? -1.0f : 1.0f;
            float txr = (float)w + sf * r * ux * cscale;
            float tyr = (float)h + sf * r * uy * cscale;
            float tzr = (float)d + sf * r * uz * cscale;
            float cx = fabsf(txr + 0.5f); float ix = fminf(cx, 96.0f - cx) - 0.5f;
            float cy = fabsf(tyr + 0.5f); float iy = fminf(cy, 96.0f - cy) - 0.5f;
            float cz = fabsf(tzr + 0.5f); float iz = fminf(cz, 96.0f - cz) - 0.5f;
            float x0f = floorf(ix), y0f = floorf(iy), z0f = floorf(iz);
            float fx = ix - x0f, fy = iy - y0f, fz = iz - z0f;
            int x0 = min(max((int)x0f, 0), 47); int x1 = min(x0 + 1, 47);
            int y0 = min(max((int)y0f, 0), 47); int y1 = min(y0 + 1, 47);
            int z0 = min(max((int)z0f, 0), 47); int z1 = min(z0 + 1, 47);
            float fxe = (x1 == x0) ? 0.0f : fx;  // reference's clipped-x1 semantics
            _Float16 hx = (_Float16)fxe, hy = (_Float16)fy, hz = (_Float16)fz;
            fx2[si] = (h2){hx, hx}; fy2[si] = (h2){hy, hy}; fz2[si] = (h2){hz, hz};
            int lz0 = z0 - zlo, lz1 = z1 - zlo;
            int ly0 = y0 - ylo, ly1 = y1 - ylo;
            int lx0 = x0 - xlo;
            int i00 = (lz0 * 13 + ly0) * 13 + lx0;
            int i01 = (lz0 * 13 + ly1) * 13 + lx0;
            int i10 = (lz1 * 13 + ly0) * 13 + lx0;
            int i11 = (lz1 * 13 + ly1) * 13 + lx0;
            a00s[si] = swze(i00) * 8; a00p[si] = swze(i00 + 1) * 8;
            a01s[si] = swze(i01) * 8; a01p[si] = swze(i01 + 1) * 8;
            a10s[si] = swze(i10) * 8; a10p[si] = swze(i10 + 1) * 8;
            a11s[si] = swze(i11) * 8; a11p[si] = swze(i11 + 1) * 8;
        }
    }

    // ---- zero pad slots [1520,1534] in both buffers (swz(1520)=1535 is real) ----
    if (tid < 30) {
        int b = tid / 15, j = tid % 15;
        *(q4*)(tbuf + b * TILE_BYTES + (1520 + j) * 8) = q4{(h2){0,0}, (h2){0,0}};
    }
    // ---- stage group 0 tile into buffer 0 (swizzled slots) ----
    {
        float ld[24];
#pragma unroll
        for (int cg = 0; cg < 4; ++cg) {
            const float* xc = xn + cg * DHW;
#pragma unroll
            for (int i = 0; i < 6; ++i) ld[cg * 6 + i] = xc[goff[i]];
        }
#pragma unroll
        for (int i = 0; i < 6; ++i) {
            int e = tid + i * 256;
            if (e < TILE_N) {
                q4 vq; vq.lo = pkrtz(ld[i], ld[6 + i]); vq.hi = pkrtz(ld[12 + i], ld[18 + i]);
                *(q4*)(tbuf + soff[i]) = vq;
            }
        }
    }

    // ---- preload group 1 into pqv registers (staged at top of iter 0) ----
    q4 pqv[6];
    {
        float l2[24];
#pragma unroll
        for (int cg = 0; cg < 4; ++cg) {
            const float* xc = xn + (4 + cg) * DHW;
#pragma unroll
            for (int i = 0; i < 6; ++i) l2[cg * 6 + i] = xc[goff[i]];
        }
#pragma unroll
        for (int i = 0; i < 6; ++i) {
            pqv[i].lo = pkrtz(l2[i], l2[6 + i]);
            pqv[i].hi = pkrtz(l2[12 + i], l2[18 + i]);
        }
    }
    __syncthreads();

    floatx4 acc[4][2];
#pragma unroll
    for (int mt = 0; mt < 4; ++mt)
#pragma unroll
        for (int nt = 0; nt < 2; ++nt) acc[mt][nt] = (floatx4){0.f, 0.f, 0.f, 0.f};

    const int selfB = swze(((lz + 2) * 13 + (ly + 2)) * 13 + (lx + 2)) * 8;
    const unsigned short* bt = (const unsigned short*)(ws + WS_BT_F);
    const int tokq = (tid >> 3) & 3;           // token-quadrant swizzle key
    const int qm = lane >> 4, nlo = lane & 15;
    const h2 HHALF = dup2(0.5f);

    // B-fragment rolling prefetch (hidden under trilinear compute)
    short8 bc0 = *(const short8*)(bt + (nlo * 256 + qm * 8));
    short8 bc1 = *(const short8*)(bt + ((nlo + 16) * 256 + qm * 8));

#pragma unroll 2
    for (int g = 0; g < GROUPS; ++g) {
        const int rb = (g & 1);                // read buffer (compile-time after unroll)
        const int wb = rb ^ 1;                 // write buffer (group g+1)
        // ---- stage-early: write group g+1's tile from pqv (reg->LDS, no wait) ----
        if (g < GROUPS - 1) {
#pragma unroll
            for (int i = 0; i < 6; ++i) {
                int e = tid + i * 256;
                if (e < TILE_N)
                    *(q4*)(tbuf + wb * TILE_BYTES + soff[i]) = pqv[i];
            }
        }
        // ---- issue global prefetch for group g+2 ----
        float nld[24];
        if (g < GROUPS - 2) {
            const float* xg = xn + (g + 2) * 4 * DHW;
#pragma unroll
            for (int cg = 0; cg < 4; ++cg) {
                const float* xc = xg + cg * DHW;
#pragma unroll
                for (int i = 0; i < 6; ++i) nld[cg * 6 + i] = xc[goff[i]];
            }
        }
        short8 bn0 = bc0, bn1 = bc1;
        if (g < GROUPS - 1) {
            bn0 = *(const short8*)(bt + (nlo * 256 + (g + 1) * 32 + qm * 8));
            bn1 = *(const short8*)(bt + ((nlo + 16) * 256 + (g + 1) * 32 + qm * 8));
        }
        // ---- packed trilinear: all 4 channels per site (swizzled 8B entries) ----
        const char* tb = tbuf + rb * TILE_BYTES;
        q4 sc = *(const q4*)(tb + selfB);
        q4 vv[6];
#pragma unroll
        for (int si = 0; si < 6; ++si) {
            q4 v000 = *(const q4*)(tb + a00s[si]), v001 = *(const q4*)(tb + a00p[si]);
            q4 v010 = *(const q4*)(tb + a01s[si]), v011 = *(const q4*)(tb + a01p[si]);
            q4 v100 = *(const q4*)(tb + a10s[si]), v101 = *(const q4*)(tb + a10p[si]);
            q4 v110 = *(const q4*)(tb + a11s[si]), v111 = *(const q4*)(tb + a11p[si]);
            h2 fx = fx2[si], fy = fy2[si], fz = fz2[si];
            h2 c00l = v000.lo + fx * (v001.lo - v000.lo);
            h2 c00h = v000.hi + fx * (v001.hi - v000.hi);
            h2 c01l = v010.lo + fx * (v011.lo - v010.lo);
            h2 c01h = v010.hi + fx * (v011.hi - v010.hi);
            h2 c10l = v100.lo + fx * (v101.lo - v100.lo);
            h2 c10h = v100.hi + fx * (v101.hi - v100.hi);
            h2 c11l = v110.lo + fx * (v111.lo - v110.lo);
            h2 c11h = v110.hi + fx * (v111.hi - v110.hi);
            h2 c0l = c00l + fy * (c01l - c00l);
            h2 c0h = c00h + fy * (c01h - c00h);
            h2 c1l = c10l + fy * (c11l - c10l);
            h2 c1h = c10h + fy * (c11h - c10h);
            vv[si].lo = c0l + fz * (c1l - c0l);
            vv[si].hi = c0h + fz * (c1h - c0h);
        }
        // ---- token assembly: packed f16 math on channel pairs ----
#pragma unroll
        for (int pr = 0; pr < 2; ++pr) {
            h2 X  = pr ? sc.hi : sc.lo;
            h2 V0 = pr ? vv[0].hi : vv[0].lo;
            h2 V1 = pr ? vv[1].hi : vv[1].lo;
            h2 V2 = pr ? vv[2].hi : vv[2].lo;
            h2 V3 = pr ? vv[3].hi : vv[3].lo;
            h2 V4 = pr ? vv[4].hi : vv[4].lo;
            h2 V5 = pr ? vv[5].hi : vv[5].lo;
            h2 xv2 = X + X;
            h2 s0 = V0 + V1, dm0 = V0 - V1;
            h2 t1 = HHALF * s0;
            h2 d0 = dm0 * hir[0];
            h2 gx = d0 * hux[0], gy = d0 * huy[0], gz = d0 * huz[0];
            h2 l  = (s0 - xv2) * hq[0];
            h2 s1 = V2 + V3, dm1 = V2 - V3;
            h2 t2 = HHALF * s1;
            h2 d1 = dm1 * hir[1];
            gx = d1 * hux[1] + gx; gy = d1 * huy[1] + gy; gz = d1 * huz[1] + gz;
            l  = (s1 - xv2) * hq[1] + l;
            h2 s2v = V4 + V5, dm2 = V4 - V5;
            h2 t3 = HHALF * s2v;
            h2 d2 = dm2 * hir[2];
            gx = d2 * hux[2] + gx; gy = d2 * huy[2] + gy; gz = d2 * huz[2] + gz;
            l  = (s2v - xv2) * hq[2] + l;
            // word packing: .x channel takes lo16s, .y channel hi16s
            uint4 twa, twb;
            twa.x = __builtin_amdgcn_perm(h2u(t1), h2u(X),  0x05040100u);
            twa.y = __builtin_amdgcn_perm(h2u(t3), h2u(t2), 0x05040100u);
            twa.z = __builtin_amdgcn_perm(h2u(gy), h2u(gx), 0x05040100u);
            twa.w = __builtin_amdgcn_perm(h2u(l),  h2u(gz), 0x05040100u);
            twb.x = __builtin_amdgcn_perm(h2u(t1), h2u(X),  0x07060302u);
            twb.y = __builtin_amdgcn_perm(h2u(t3), h2u(t2), 0x07060302u);
            twb.z = __builtin_amdgcn_perm(h2u(gy), h2u(gx), 0x07060302u);
            twb.w = __builtin_amdgcn_perm(h2u(l),  h2u(gz), 0x07060302u);
            int qa = (2 * pr)     ^ tokq;
            int qb = (2 * pr + 1) ^ tokq;
            *(uint4*)(tokb + tid * TOK_STR + qa * 16) = twa;
            *(uint4*)(tokb + tid * TOK_STR + qb * 16) = twb;
        }
        // ---- MFMA: K-chunk g (k = g*32 .. g*32+31), fp16 ----
        // Tokens are wave-private: in-order per-wave LDS suffices, no barrier.
        {
            half8 hb0 = __builtin_bit_cast(half8, bc0);
            half8 hb1 = __builtin_bit_cast(half8, bc1);
#pragma unroll
            for (int mt = 0; mt < 4; ++mt) {
                int row = w64 + mt * 16 + nlo;
                int qe  = qm ^ ((row >> 3) & 3);
                half8 a = __builtin_bit_cast(half8,
                          *(const short8*)(tokb + row * TOK_STR + qe * 16));
                acc[mt][0] = __builtin_amdgcn_mfma_f32_16x16x32_f16(a, hb0, acc[mt][0], 0, 0, 0);
                acc[mt][1] = __builtin_amdgcn_mfma_f32_16x16x32_f16(a, hb1, acc[mt][1], 0, 0, 0);
            }
        }
        bc0 = bn0; bc1 = bn1;

        // ---- pack g+2's loads into pqv for next iteration's stage ----
        if (g < GROUPS - 2) {
#pragma unroll
            for (int i = 0; i < 6; ++i) {
                pqv[i].lo = pkrtz(nld[i], nld[6 + i]);
                pqv[i].hi = pkrtz(nld[12 + i], nld[18 + i]);
            }
        }
        __syncthreads();   // single rendezvous: buf[wb] staged, buf[rb] reads done
    }

    // ---- C writeback via LDS (col-swizzled, conflict-free) ----
    {
#pragma unroll
        for (int mt = 0; mt < 4; ++mt)
#pragma unroll
            for (int nt = 0; nt < 2; ++nt)
#pragma unroll
                for (int r = 0; r < 4; ++r) {
                    int vr = w64 + mt * 16 + qm * 4 + r;
                    int col = nt * 16 + nlo;
                    cbuf[vr * 36 + (col ^ (vr & 31))] = acc[mt][nt][r];
                }
    }
    __syncthreads();

    // ---- epilogue: out = x + delta + b_mix (coalesced, nontemporal) ----
    const float* dr = cbuf + tid * 36;
    float* on = out + (size_t)n * CH * DHW;
#pragma unroll
    for (int o = 0; o < 32; ++o)
        __builtin_nontemporal_store(
            xn[o * DHW + pos] + dr[o ^ (tid & 31)] + ws[WS_BM + o],
            on + o * DHW + pos);
}

extern "C" void kernel_launch(void* const* d_in, const int* in_sizes, int n_in,
                              void* d_out, int out_size, void* d_ws, size_t ws_size,
                              hipStream_t stream) {
    const float *x = (const float*)d_in[0], *w_field = (const float*)d_in[1],
                *b_field = (const float*)d_in[2], *gates = (const float*)d_in[3],
                *w_mix = (const float*)d_in[4], *b_mix = (const float*)d_in[5];
    for (int i = 0; i < n_in; ++i) {
        switch (in_sizes[i]) {
            case NB * CH * DHW: x       = (const float*)d_in[i]; break;
            case 12 * CH:       w_field = (const float*)d_in[i]; break;
            case 12:            b_field = (const float*)d_in[i]; break;
            case TT:            gates   = (const float*)d_in[i]; break;
            case CH * TT * CH:  w_mix   = (const float*)d_in[i]; break;
            case CH:            b_mix   = (const float*)d_in[i]; break;
            default: break;
        }
    }
    float* ws = (float*)d_ws;
    prep_kernel<<<32, 256, 0, stream>>>(w_field, b_field, gates, w_mix, b_mix, ws);
    geo_main<<<864, 256, 0, stream>>>(x, ws, (float*)d_out);
}